// Round 6
// baseline (63.892 us; speedup 1.0000x reference)
//
#include <hip/hip_runtime.h>
#include <math.h>

// VisionPooler: B=32, SEQ=2520 (84x30 grid), HIDDEN=768, OUT_LEN=280, k=3.
// out = concat( [B,280,768] pooled f32 , [B,280] mask-as-f32 ).
//
// k_verify (32 blocks): int4-vectorized check that pos[b] is the regular grid
//   (x==s%84, y==s/84). regular -> flags[b]=1. irregular -> flags[b]=0 and
//   builds generic bucket lists (entry=(s<<1)|pad, sentinel 1) + mask.
// k_pool (70x32 blocks, 192 thr): each block = 4 consecutive buckets of one
//   bucket-row: reads 3 y-rows x 12 contiguous patches (3x36KB contiguous),
//   writes 12KB contiguous. Fast path = pure formula; slow path = lists.
// ws: int flags[32] @0 ; int ents[32*280*16] @128B  (573,568 B total).

#define NB    32
#define SEQL  2520
#define HID   768
#define OUTL  280
#define CAP   16
#define GX    84        // grid x extent when regular
#define KP    3         // pool factor
#define MXK   (GX / KP) // 28 buckets per row when regular
#define LPB   4         // buckets per k_pool block
#define GPR   (MXK / LPB) // 7 groups per bucket-row

typedef float f32x4 __attribute__((ext_vector_type(4)));

__global__ void __launch_bounds__(256)
k_verify(const int* __restrict__ pos, const int* __restrict__ padding,
         int* __restrict__ flags, int* __restrict__ ents,
         float* __restrict__ out_mask) {
    __shared__ int r_ok[256];
    __shared__ int r_mx[256];
    __shared__ int s_cnt[OUTL];
    __shared__ int s_ent[OUTL * CAP];
    const int b = blockIdx.x;
    const int t = threadIdx.x;
    const int* p = pos + (size_t)b * SEQL * 2;
    const int4* p4 = (const int4*)p;          // {x0,y0,x1,y1} per 2 patches

    int ok = 1, m = 0;
    for (int i = t; i < SEQL / 2; i += 256) { // 1260 int4s
        int4 v = p4[i];
        int s0 = 2 * i, s1 = 2 * i + 1;
        ok &= (v.x == s0 % GX) & (v.y == s0 / GX)
            & (v.z == s1 % GX) & (v.w == s1 / GX);
        int cx = v.x < 0 ? 0 : v.x; if (cx > m) m = cx;
        cx = v.z < 0 ? 0 : v.z;     if (cx > m) m = cx;
    }
    r_ok[t] = ok; r_mx[t] = m;
    __syncthreads();
    for (int off = 128; off > 0; off >>= 1) {
        if (t < off) {
            r_ok[t] &= r_ok[t + off];
            int o = r_mx[t + off]; if (o > r_mx[t]) r_mx[t] = o;
        }
        __syncthreads();
    }
    if (r_ok[0]) {                       // regular grid: nothing else needed
        if (t == 0) flags[b] = 1;
        return;
    }

    // ---- generic fallback: build bucket lists ----
    const int mxk = (r_mx[0] + 1) / KP;
    for (int i = t; i < OUTL; i += 256) s_cnt[i] = 0;
    for (int i = t; i < OUTL * CAP; i += 256) s_ent[i] = 1;  // sentinel: pad bit
    __syncthreads();
    const int* pd = padding + (size_t)b * SEQL;
    for (int s = t; s < SEQL; s += 256) {
        int x = p[2 * s];     if (x < 0) x = 0;
        int y = p[2 * s + 1]; if (y < 0) y = 0;
        int seg = x / KP + mxk * (y / KP);
        if (seg >= 0 && seg < OUTL) {    // jax segment_sum drops out-of-range
            int slot = atomicAdd(&s_cnt[seg], 1);
            if (slot < CAP)
                s_ent[seg * CAP + slot] = (s << 1) | (pd[s] != 0 ? 1 : 0);
        }
    }
    __syncthreads();
    int* eg = ents + (size_t)b * OUTL * CAP;
    for (int i = t; i < OUTL * CAP; i += 256) eg[i] = s_ent[i];
    for (int i = t; i < OUTL; i += 256)
        out_mask[b * OUTL + i] = (s_cnt[i] > 0) ? 1.0f : 0.0f;
    if (t == 0) flags[b] = 0;
}

// One block per (bucket-group g, batch b). 192 threads = one float4 lane of
// HID; each block covers 4 consecutive buckets (12 patch-columns x 3 rows).
__global__ void __launch_bounds__(192)
k_pool(const float* __restrict__ hs, const int* __restrict__ padding,
       const int* __restrict__ flags, const int* __restrict__ ents,
       float* __restrict__ out, float* __restrict__ out_mask, float scale) {
    __shared__ int spad[3 * 3 * LPB];   // pad bit per (dy, j)
    __shared__ int se[LPB][9];          // slow path entries
    const int g = blockIdx.x;           // 0..69
    const int b = blockIdx.y;
    const int t = threadIdx.x;
    const int yk = g / GPR;             // bucket row 0..9
    const int x0 = (g % GPR) * KP * LPB;// patch col base (12-wide)
    const int l0 = yk * MXK + (g % GPR) * LPB;
    const int fast = flags[b];

    if (fast) {
        if (t < 3 * 3 * LPB) {          // 36 pad bits, contiguous per row
            int dy = t / (3 * LPB), j = t % (3 * LPB);
            int s = (KP * yk + dy) * GX + x0 + j;
            spad[t] = (padding[b * SEQL + s] != 0);
        }
        if (t < LPB) out_mask[b * OUTL + l0 + t] = 1.0f;
    } else if (t < LPB) {
        int e[9];
        const int* eg = ents + ((size_t)b * OUTL + l0 + t) * CAP;
        #pragma unroll
        for (int i = 0; i < 9; ++i) e[i] = eg[i];
        #pragma unroll
        for (int i = 1; i < 9; ++i) {   // sort ascending: deterministic order
            int v = e[i], j = i - 1;
            while (j >= 0 && e[j] > v) { e[j + 1] = e[j]; --j; }
            e[j + 1] = v;
        }
        #pragma unroll
        for (int i = 0; i < 9; ++i) se[t][i] = e[i];
    }
    __syncthreads();

    f32x4 acc[LPB];
    #pragma unroll
    for (int q = 0; q < LPB; ++q) acc[q] = (f32x4)(0.f);
    const f32x4* base = (const f32x4*)(hs + (size_t)b * SEQL * HID);

    if (fast) {
        #pragma unroll
        for (int dy = 0; dy < 3; ++dy) {
            const int row_s = (KP * yk + dy) * GX + x0;
            #pragma unroll
            for (int j = 0; j < 3 * LPB; ++j) {
                if (!spad[dy * 3 * LPB + j]) {       // block-uniform branch
                    f32x4 v = __builtin_nontemporal_load(
                        base + (size_t)(row_s + j) * (HID / 4) + t);
                    acc[j / KP] += v;
                }
            }
        }
    } else {
        #pragma unroll
        for (int q = 0; q < LPB; ++q) {
            #pragma unroll
            for (int i = 0; i < 9; ++i) {
                int e = se[q][i];
                if (!(e & 1)) {
                    f32x4 v = __builtin_nontemporal_load(
                        base + (size_t)(e >> 1) * (HID / 4) + t);
                    acc[q] += v;
                }
            }
        }
    }

    f32x4* og = (f32x4*)(out + (size_t)(b * OUTL + l0) * HID) + t;
    #pragma unroll
    for (int q = 0; q < LPB; ++q) {
        acc[q] *= scale;
        __builtin_nontemporal_store(acc[q], og + (size_t)q * (HID / 4));
    }
}

extern "C" void kernel_launch(void* const* d_in, const int* in_sizes, int n_in,
                              void* d_out, int out_size, void* d_ws, size_t ws_size,
                              hipStream_t stream) {
    const float* hs      = (const float*)d_in[0];
    const int*   pos     = (const int*)d_in[1];
    const int*   padding = (const int*)d_in[2]; // jax bool -> 4-byte on device
    // d_in[3] = output_length scalar (unused; shapes fixed: 2520 -> 280, k=3)

    int* flags = (int*)d_ws;                    // [32]
    int* ents  = (int*)((char*)d_ws + 128);     // [32*280*16]

    float* out      = (float*)d_out;
    float* out_mask = out + (size_t)NB * OUTL * HID;
    const float scale = sqrtf((float)HID) / 9.0f;   // *sqrt(768) / k^2

    k_verify<<<NB, 256, 0, stream>>>(pos, padding, flags, ents, out_mask);
    dim3 grid(OUTL / LPB / (MXK / LPB) * GPR, NB);  // 70 x 32
    k_pool<<<grid, 192, 0, stream>>>(hs, padding, flags, ents, out, out_mask, scale);
}

// Round 7
// 51.131 us; speedup vs baseline: 1.2496x; 1.2496x over previous
//
#include <hip/hip_runtime.h>
#include <math.h>

// VisionPooler: B=32, SEQ=2520 (84x30 grid), HIDDEN=768, OUT_LEN=280, k=3.
// out = concat( [B,280,768] pooled f32 , [B,280] mask-as-f32 ).
//
// k_verify (32 blocks): int4-vectorized check that pos[b] is the regular grid
//   (x==s%84, y==s/84). regular -> flags[b]=1. irregular -> flags[b]=0 and
//   builds generic bucket lists (entry=(s<<1)|pad, sentinel 1) + mask.
// k_pool (280x32 blocks, 192 thr, NO LDS/barrier): fast path derives its 9
//   source rows by formula and reads 9 pad ints (block-uniform -> broadcast);
//   slow path reads + register-sorts its bucket's 9 list entries.
// ws: int flags[32] @0 ; int ents[32*280*16] @128B  (573,568 B total).

#define NB    32
#define SEQL  2520
#define HID   768
#define OUTL  280
#define CAP   16
#define GX    84        // grid x extent when regular
#define KP    3         // pool factor
#define MXK   (GX / KP) // 28 buckets per row when regular

typedef float f32x4 __attribute__((ext_vector_type(4)));

__global__ void __launch_bounds__(256)
k_verify(const int* __restrict__ pos, const int* __restrict__ padding,
         int* __restrict__ flags, int* __restrict__ ents,
         float* __restrict__ out_mask) {
    __shared__ int r_ok[256];
    __shared__ int r_mx[256];
    __shared__ int s_cnt[OUTL];
    __shared__ int s_ent[OUTL * CAP];
    const int b = blockIdx.x;
    const int t = threadIdx.x;
    const int* p = pos + (size_t)b * SEQL * 2;
    const int4* p4 = (const int4*)p;          // {x0,y0,x1,y1} per 2 patches

    int ok = 1, m = 0;
    for (int i = t; i < SEQL / 2; i += 256) { // 1260 int4s
        int4 v = p4[i];
        int s0 = 2 * i, s1 = 2 * i + 1;
        ok &= (v.x == s0 % GX) & (v.y == s0 / GX)
            & (v.z == s1 % GX) & (v.w == s1 / GX);
        int cx = v.x < 0 ? 0 : v.x; if (cx > m) m = cx;
        cx = v.z < 0 ? 0 : v.z;     if (cx > m) m = cx;
    }
    r_ok[t] = ok; r_mx[t] = m;
    __syncthreads();
    for (int off = 128; off > 0; off >>= 1) {
        if (t < off) {
            r_ok[t] &= r_ok[t + off];
            int o = r_mx[t + off]; if (o > r_mx[t]) r_mx[t] = o;
        }
        __syncthreads();
    }
    if (r_ok[0]) {                       // regular grid: nothing else needed
        if (t == 0) flags[b] = 1;
        return;
    }

    // ---- generic fallback: build bucket lists ----
    const int mxk = (r_mx[0] + 1) / KP;
    for (int i = t; i < OUTL; i += 256) s_cnt[i] = 0;
    for (int i = t; i < OUTL * CAP; i += 256) s_ent[i] = 1;  // sentinel: pad bit
    __syncthreads();
    const int* pd = padding + (size_t)b * SEQL;
    for (int s = t; s < SEQL; s += 256) {
        int x = p[2 * s];     if (x < 0) x = 0;
        int y = p[2 * s + 1]; if (y < 0) y = 0;
        int seg = x / KP + mxk * (y / KP);
        if (seg >= 0 && seg < OUTL) {    // jax segment_sum drops out-of-range
            int slot = atomicAdd(&s_cnt[seg], 1);
            if (slot < CAP)
                s_ent[seg * CAP + slot] = (s << 1) | (pd[s] != 0 ? 1 : 0);
        }
    }
    __syncthreads();
    int* eg = ents + (size_t)b * OUTL * CAP;
    for (int i = t; i < OUTL * CAP; i += 256) eg[i] = s_ent[i];
    for (int i = t; i < OUTL; i += 256)
        out_mask[b * OUTL + i] = (s_cnt[i] > 0) ? 1.0f : 0.0f;
    if (t == 0) flags[b] = 0;
}

// One block per (bucket l, batch b). 192 threads, one float4 of HID each.
// No LDS, no barriers: per-thread block-uniform metadata (broadcast loads).
__global__ void __launch_bounds__(192)
k_pool(const float* __restrict__ hs, const int* __restrict__ padding,
       const int* __restrict__ flags, const int* __restrict__ ents,
       float* __restrict__ out, float* __restrict__ out_mask, float scale) {
    const int l = blockIdx.x;
    const int b = blockIdx.y;
    const int t = threadIdx.x;
    const int bl = b * OUTL + l;

    int e[9];                            // (s<<1)|pad, ascending s
    if (flags[b]) {
        // regular: bucket l <-> (xk,yk)=(l%MXK, l/MXK); sources by formula
        const int s00 = (KP * (l / MXK)) * GX + KP * (l % MXK);
        #pragma unroll
        for (int dy = 0; dy < 3; ++dy)
            #pragma unroll
            for (int dx = 0; dx < 3; ++dx) {
                int s = s00 + dy * GX + dx;
                e[dy * 3 + dx] = (s << 1) | (padding[b * SEQL + s] != 0 ? 1 : 0);
            }
        if (t == 0) out_mask[bl] = 1.0f; // every bucket gets 9 patches
    } else {
        const int* eg = ents + (size_t)bl * CAP;
        #pragma unroll
        for (int i = 0; i < 9; ++i) e[i] = eg[i];
        #pragma unroll
        for (int i = 1; i < 9; ++i) {    // sort ascending: deterministic order
            int v = e[i], j = i - 1;
            while (j >= 0 && e[j] > v) { e[j + 1] = e[j]; --j; }
            e[j + 1] = v;
        }
        // mask already written by k_verify in this case
    }

    f32x4 acc = (f32x4)(0.f);
    const f32x4* base = (const f32x4*)(hs + (size_t)b * SEQL * HID);
    #pragma unroll
    for (int i = 0; i < 9; ++i) {
        if (!(e[i] & 1)) {               // block-uniform -> no divergence
            f32x4 v = __builtin_nontemporal_load(
                base + (size_t)(e[i] >> 1) * (HID / 4) + t);
            acc += v;
        }
    }
    acc *= scale;
    __builtin_nontemporal_store(acc, (f32x4*)(out + (size_t)bl * HID) + t);
}

extern "C" void kernel_launch(void* const* d_in, const int* in_sizes, int n_in,
                              void* d_out, int out_size, void* d_ws, size_t ws_size,
                              hipStream_t stream) {
    const float* hs      = (const float*)d_in[0];
    const int*   pos     = (const int*)d_in[1];
    const int*   padding = (const int*)d_in[2]; // jax bool -> 4-byte on device
    // d_in[3] = output_length scalar (unused; shapes fixed: 2520 -> 280, k=3)

    int* flags = (int*)d_ws;                    // [32]
    int* ents  = (int*)((char*)d_ws + 128);     // [32*280*16]

    float* out      = (float*)d_out;
    float* out_mask = out + (size_t)NB * OUTL * HID;
    const float scale = sqrtf((float)HID) / 9.0f;   // *sqrt(768) / k^2

    k_verify<<<NB, 256, 0, stream>>>(pos, padding, flags, ents, out_mask);
    dim3 grid(OUTL, NB);
    k_pool<<<grid, 192, 0, stream>>>(hs, padding, flags, ents, out, out_mask, scale);
}